// Round 1
// baseline (1656.889 us; speedup 1.0000x reference)
//
#include <hip/hip_runtime.h>
#include <hip/hip_fp16.h>

#define TT 2048
#define BB 64
#define HH 128
#define GG 512   // 4H
#define CH 64    // chunk (timesteps per handshake)
#define NCH (TT / CH)

typedef _Float16 f16x8 __attribute__((ext_vector_type(8)));
typedef _Float16 f16x4 __attribute__((ext_vector_type(4)));
typedef float f32x4 __attribute__((ext_vector_type(4)));

__device__ __forceinline__ float sigm(float x) {
    return __builtin_amdgcn_rcpf(1.0f + __expf(-x));
}
__device__ __forceinline__ float tanh_f(float x) {
    return 1.0f - 2.0f * __builtin_amdgcn_rcpf(1.0f + __expf(2.0f * x));
}
// LDS-only barrier: no vmcnt drain (HIP __syncthreads drains all global ops).
__device__ __forceinline__ void bar_lds() {
    asm volatile("s_waitcnt lgkmcnt(0)\n\ts_barrier" ::: "memory");
}

__device__ __forceinline__ f16x8 load_frag(const float* rowp, int kt, int lh) {
    const float4* p4 = (const float4*)(rowp + kt * 32 + lh * 8);
    float4 a = p4[0], b = p4[1];
    f16x8 f;
    f[0] = (_Float16)a.x; f[1] = (_Float16)a.y; f[2] = (_Float16)a.z; f[3] = (_Float16)a.w;
    f[4] = (_Float16)b.x; f[5] = (_Float16)b.y; f[6] = (_Float16)b.z; f[7] = (_Float16)b.w;
    return f;
}

// Round 17: 4-wave (256-thread) blocks, 1 wave/SIMD via __launch_bounds__(256,1).
// Theory: the step is latency-bound and the 512-thread shape's 2 waves/SIMD run
// in barrier lockstep, serializing both waves' VALU+MFMA issue inside every
// step (~2x the single-wave path, matching the measured ~1500cyc step vs the
// ~650cyc wave path). 4 waves on 4 SIMDs = zero SIMD sharing + narrower
// per-step barrier. Cost: each wave now owns 2 column-tiles (32 cols, 32
// MFMAs/step, 128 weight VGPRs resident) — which is exactly why this needs
// (256,1): per-wave VGPR cap 512, vs the 256 cap that collapsed the allocator
// in the failed 512/1024-thread "fatter wave" attempts (rounds 13-15).
// Step math is byte-identical to the r16 champion; only the wave->column map,
// the chunk-GEMM map, and the spin granularity (s_sleep 8->2) changed.
__global__ __launch_bounds__(256, 1) void k_pipe(
    const float* __restrict__ x, const int* __restrict__ lengths,
    const float* __restrict__ ff_w, const float* __restrict__ ff_b,
    const float* __restrict__ W_ih0, const float* __restrict__ W_hh0,
    const float* __restrict__ b0, const float* __restrict__ W_ih1,
    const float* __restrict__ W_hh1, const float* __restrict__ b1,
    _Float16* __restrict__ h0g, int* __restrict__ flags,
    float* __restrict__ pooled) {
    const int tid = threadIdx.x;
    const int w = tid >> 6;        // 4 waves
    const int lane = tid & 63;
    const int c = lane & 15;
    const int lh = lane >> 4;
    const int un0 = 32 * w + c;    // first owned column
    const int un1 = un0 + 16;      // second owned column
    const bool ard = (c == 0);     // A-frag reader lanes (M=1 row 0)
    const bool wr16 = (lane < 16); // C row m=0 lanes (lh==0)

    __shared__ float xs[TT];                 // producer
    __shared__ _Float16 Hb0[2][HH];          // producer
    __shared__ _Float16 Hb1[2][HH];          // consumer
    __shared__ _Float16 Qs[CH][GG];          // consumer: chunk gates (64 KB)

    if (blockIdx.x < BB) {
        // ======================= PRODUCER: layer 0 =======================
        const int b = blockIdx.x;
        for (int i = tid; i < TT; i += 256) xs[i] = x[b * TT + i];
        ((_Float16*)Hb0)[tid] = (_Float16)0.f;  // 256 threads == 2*HH

        f16x8 Bf[2][4][4];
        float v[2][4], u0[2][4];
#pragma unroll
        for (int tile = 0; tile < 2; ++tile)
#pragma unroll
            for (int t2 = 0; t2 < 4; ++t2) {
                const int r = t2 * HH + 32 * w + 16 * tile + c;
#pragma unroll
                for (int kt = 0; kt < 4; ++kt)
                    Bf[tile][t2][kt] = load_frag(W_hh0 + r * HH, kt, lh);
                const float4* wi4 = (const float4*)(W_ih0 + r * HH);
                const float4* fw4 = (const float4*)ff_w;
                const float4* fb4 = (const float4*)ff_b;
                float vv = 0.f, uu = 0.f;
#pragma unroll
                for (int m = 0; m < HH / 4; ++m) {
                    float4 a = wi4[m], fw = fw4[m], fb = fb4[m];
                    vv += a.x * fw.x + a.y * fw.y + a.z * fw.z + a.w * fw.w;
                    uu += a.x * fb.x + a.y * fb.y + a.z * fb.z + a.w * fb.w;
                }
                v[tile][t2] = vv;
                u0[tile][t2] = uu + b0[r];
            }
#pragma unroll
        for (int tile = 0; tile < 2; ++tile)
#pragma unroll
            for (int t2 = 0; t2 < 4; ++t2)
#pragma unroll
                for (int kt = 0; kt < 4; ++kt) asm volatile("" : "+v"(Bf[tile][t2][kt]));

        float cst[2] = {0.f, 0.f};
        f16x8 av[4];
#pragma unroll
        for (int kt = 0; kt < 4; ++kt) av[kt] = (f16x8){0, 0, 0, 0, 0, 0, 0, 0};
        __syncthreads();

#define PSTEP(T_, RB_)                                                          \
    do {                                                                        \
        if (ard) {                                                              \
            _Pragma("unroll") for (int kt = 0; kt < 4; ++kt)                    \
                av[kt] = *(const f16x8*)&Hb0[RB_][kt * 32 + lh * 8];            \
        }                                                                       \
        const float xt = xs[T_];                                                \
        float p[2][4];                                                          \
        _Pragma("unroll") for (int tile = 0; tile < 2; ++tile)                  \
        _Pragma("unroll") for (int t2 = 0; t2 < 4; ++t2) {                      \
            f32x4 alo, ahi;                                                     \
            const float ci = xt * v[tile][t2] + u0[tile][t2];                   \
            alo[0] = ci;  alo[1] = 0.f; alo[2] = 0.f; alo[3] = 0.f;             \
            ahi[0] = 0.f; ahi[1] = 0.f; ahi[2] = 0.f; ahi[3] = 0.f;             \
            alo = __builtin_amdgcn_mfma_f32_16x16x32_f16(av[0], Bf[tile][t2][0],\
                                                         alo, 0, 0, 0);         \
            ahi = __builtin_amdgcn_mfma_f32_16x16x32_f16(av[2], Bf[tile][t2][2],\
                                                         ahi, 0, 0, 0);         \
            alo = __builtin_amdgcn_mfma_f32_16x16x32_f16(av[1], Bf[tile][t2][1],\
                                                         alo, 0, 0, 0);         \
            ahi = __builtin_amdgcn_mfma_f32_16x16x32_f16(av[3], Bf[tile][t2][3],\
                                                         ahi, 0, 0, 0);         \
            p[tile][t2] = alo[0] + ahi[0];                                      \
        }                                                                       \
        _Pragma("unroll") for (int tile = 0; tile < 2; ++tile) {                \
            float gi = sigm(p[tile][0]), gf = sigm(p[tile][1]);                 \
            float gg = tanh_f(p[tile][2]), go = sigm(p[tile][3]);               \
            cst[tile] = gf * cst[tile] + gi * gg;                               \
            float h0n = go * tanh_f(cst[tile]);                                 \
            if (wr16) {                                                         \
                const int uu_ = un0 + 16 * tile;                                \
                Hb0[(RB_) ^ 1][uu_] = (_Float16)h0n;                            \
                __builtin_nontemporal_store(                                    \
                    (_Float16)h0n, h0g + ((size_t)b * TT + (T_)) * HH + uu_);   \
            }                                                                   \
        }                                                                       \
        bar_lds();                                                              \
    } while (0)

        for (int ch = 0; ch < NCH; ++ch) {
            const int t0 = ch * CH;
            for (int j = 0; j < CH; j += 2) {
                PSTEP(t0 + j, 0);
                PSTEP(t0 + j + 1, 1);
            }
            __syncthreads();  // drain every wave's h0 NT stores before signaling
            if (tid == 0)
                __hip_atomic_store(&flags[b * NCH + ch], ch + 1, __ATOMIC_RELEASE,
                                   __HIP_MEMORY_SCOPE_AGENT);
        }
#undef PSTEP
    } else {
        // ======================= CONSUMER: layer 1 =======================
        const int b = blockIdx.x - BB;
        ((_Float16*)Hb1)[tid] = (_Float16)0.f;  // 256 threads == 2*HH

        f16x8 Bh[2][4][4];
        float bb1[2][4];
#pragma unroll
        for (int tile = 0; tile < 2; ++tile)
#pragma unroll
            for (int t2 = 0; t2 < 4; ++t2) {
                const int r = t2 * HH + 32 * w + 16 * tile + c;
#pragma unroll
                for (int kt = 0; kt < 4; ++kt)
                    Bh[tile][t2][kt] = load_frag(W_hh1 + r * HH, kt, lh);
                bb1[tile][t2] = b1[r];
            }
#pragma unroll
        for (int tile = 0; tile < 2; ++tile)
#pragma unroll
            for (int t2 = 0; t2 < 4; ++t2)
#pragma unroll
                for (int kt = 0; kt < 4; ++kt) asm volatile("" : "+v"(Bh[tile][t2][kt]));

        const int len = lengths[b];
        float cst[2] = {0.f, 0.f};
        float mean[2] = {0.f, 0.f}, mx[2] = {-1e30f, -1e30f}, last[2] = {0.f, 0.f};
        f16x8 av[4];
#pragma unroll
        for (int kt = 0; kt < 4; ++kt) av[kt] = (f16x8){0, 0, 0, 0, 0, 0, 0, 0};
        __syncthreads();

#define CSTEP(T_, RB_)                                                          \
    do {                                                                        \
        const int jj = (T_) & (CH - 1);                                         \
        f16x4 qv0 = *(const f16x4*)&Qs[jj][un0 * 4]; /* broadcast */            \
        f16x4 qv1 = *(const f16x4*)&Qs[jj][un1 * 4];                            \
        if (ard) {                                                              \
            _Pragma("unroll") for (int kt = 0; kt < 4; ++kt)                    \
                av[kt] = *(const f16x8*)&Hb1[RB_][kt * 32 + lh * 8];            \
        }                                                                       \
        float p[2][4];                                                          \
        _Pragma("unroll") for (int tile = 0; tile < 2; ++tile)                  \
        _Pragma("unroll") for (int t2 = 0; t2 < 4; ++t2) {                      \
            f32x4 alo, ahi;                                                     \
            alo[0] = (float)(tile ? qv1[t2] : qv0[t2]);                         \
            alo[1] = 0.f; alo[2] = 0.f; alo[3] = 0.f;                           \
            ahi[0] = 0.f; ahi[1] = 0.f; ahi[2] = 0.f; ahi[3] = 0.f;             \
            alo = __builtin_amdgcn_mfma_f32_16x16x32_f16(av[0], Bh[tile][t2][0],\
                                                         alo, 0, 0, 0);         \
            ahi = __builtin_amdgcn_mfma_f32_16x16x32_f16(av[2], Bh[tile][t2][2],\
                                                         ahi, 0, 0, 0);         \
            alo = __builtin_amdgcn_mfma_f32_16x16x32_f16(av[1], Bh[tile][t2][1],\
                                                         alo, 0, 0, 0);         \
            ahi = __builtin_amdgcn_mfma_f32_16x16x32_f16(av[3], Bh[tile][t2][3],\
                                                         ahi, 0, 0, 0);         \
            p[tile][t2] = alo[0] + ahi[0];                                      \
        }                                                                       \
        _Pragma("unroll") for (int tile = 0; tile < 2; ++tile) {                \
            float gi = sigm(p[tile][0]), gf = sigm(p[tile][1]);                 \
            float gg = tanh_f(p[tile][2]), go = sigm(p[tile][3]);               \
            cst[tile] = gf * cst[tile] + gi * gg;                               \
            float h1n = go * tanh_f(cst[tile]);                                 \
            if (wr16) Hb1[(RB_) ^ 1][un0 + 16 * tile] = (_Float16)h1n;          \
            if ((T_) < len) {                                                   \
                mean[tile] += h1n;                                              \
                mx[tile] = fmaxf(mx[tile], h1n);                                \
            }                                                                   \
            if ((T_) == len - 1) last[tile] = h1n;                              \
        }                                                                       \
        bar_lds();                                                              \
    } while (0)

        for (int ch = 0; ch < NCH; ++ch) {
            if (tid == 0) {  // acquire gate
                int guard = 0;
                while (__hip_atomic_load(&flags[b * NCH + ch], __ATOMIC_ACQUIRE,
                                         __HIP_MEMORY_SCOPE_AGENT) != ch + 1) {
                    __builtin_amdgcn_s_sleep(2);
                    if (++guard > (1 << 24)) break;  // hang guard
                }
            }
            __syncthreads();
            // ---- chunk GEMM: Qs[j][col*4+t2] = b1 + W_ih1 . h0[t0+j] ----
            const _Float16* hbase = h0g + ((size_t)b * TT + ch * CH) * HH;
#pragma unroll
            for (int tile = 0; tile < 2; ++tile) {
                f16x8 Bi[4][4];  // reloaded per chunk/tile (transient)
#pragma unroll
                for (int t2 = 0; t2 < 4; ++t2)
#pragma unroll
                    for (int kt = 0; kt < 4; ++kt)
                        Bi[t2][kt] = load_frag(
                            W_ih1 + (t2 * HH + 32 * w + 16 * tile + c) * HH, kt, lh);
#pragma unroll
                for (int mt = 0; mt < 4; ++mt) {
                    f16x8 am[4];  // A[m=c][k=kt*32+lh*8+j]
#pragma unroll
                    for (int kt = 0; kt < 4; ++kt)
                        am[kt] = *(const f16x8*)(hbase + (mt * 16 + c) * HH + kt * 32 + lh * 8);
                    f32x4 qa[4];
#pragma unroll
                    for (int t2 = 0; t2 < 4; ++t2) {
                        qa[t2] = (f32x4){0.f, 0.f, 0.f, 0.f};
#pragma unroll
                        for (int kt = 0; kt < 4; ++kt)
                            qa[t2] = __builtin_amdgcn_mfma_f32_16x16x32_f16(
                                am[kt], Bi[t2][kt], qa[t2], 0, 0, 0);
                    }
#pragma unroll
                    for (int r = 0; r < 4; ++r) {  // C row m = 4*lh + r
                        f16x4 qv;
#pragma unroll
                        for (int t2 = 0; t2 < 4; ++t2)
                            qv[t2] = (_Float16)(qa[t2][r] + bb1[tile][t2]);
                        *(f16x4*)&Qs[mt * 16 + 4 * lh + r][(un0 + 16 * tile) * 4] = qv;
                    }
                }
            }
            __syncthreads();  // Qs visible to all waves
            // ---- 64 recurrence steps, gates from LDS ----
            const int t0 = ch * CH;
            for (int j = 0; j < CH; j += 2) {
                CSTEP(t0 + j, 0);
                CSTEP(t0 + j + 1, 1);
            }
        }
#undef CSTEP
        if (wr16) {
#pragma unroll
            for (int tile = 0; tile < 2; ++tile) {
                const int uu_ = un0 + 16 * tile;
                pooled[b * 384 + uu_] = mean[tile] / (float)len;
                pooled[b * 384 + 128 + uu_] = mx[tile];
                pooled[b * 384 + 256 + uu_] = last[tile];
            }
        }
    }
}

// ---------------- head: [B,3H] @ [3H,C]^T + bias ----------------
__global__ __launch_bounds__(448) void k_head(
    const float* __restrict__ pooled, const float* __restrict__ lin_w,
    const float* __restrict__ lin_b, float* __restrict__ out) {
    int tid = threadIdx.x;  // 448 = 64*7
    int b = tid / 7, cc = tid % 7;
    const float* p = pooled + b * 384;
    const float* wr = lin_w + cc * 384;
    float a0 = 0.f, a1 = 0.f, a2 = 0.f, a3 = 0.f;
#pragma unroll
    for (int k = 0; k < 384; k += 4) {
        a0 += p[k + 0] * wr[k + 0];
        a1 += p[k + 1] * wr[k + 1];
        a2 += p[k + 2] * wr[k + 2];
        a3 += p[k + 3] * wr[k + 3];
    }
    out[tid] = lin_b[cc] + ((a0 + a1) + (a2 + a3));
}

extern "C" void kernel_launch(void* const* d_in, const int* in_sizes, int n_in,
                              void* d_out, int out_size, void* d_ws, size_t ws_size,
                              hipStream_t stream) {
    const float* x     = (const float*)d_in[0];
    const int*   lens  = (const int*)d_in[1];
    const float* ff_w  = (const float*)d_in[2];
    const float* ff_b  = (const float*)d_in[3];
    const float* W_ih0 = (const float*)d_in[4];
    const float* W_hh0 = (const float*)d_in[5];
    const float* b0    = (const float*)d_in[6];
    const float* W_ih1 = (const float*)d_in[7];
    const float* W_hh1 = (const float*)d_in[8];
    const float* b1    = (const float*)d_in[9];
    const float* lin_w = (const float*)d_in[10];
    const float* lin_b = (const float*)d_in[11];
    float* out = (float*)d_out;

    char* ws = (char*)d_ws;
    const size_t HBYTES = (size_t)BB * TT * HH * 2;  // 32 MB fp16 h0
    _Float16* h0g = (_Float16*)ws;
    int* flags    = (int*)(ws + HBYTES);             // 64*32 ints (poison-safe)
    float* pooled = (float*)(ws + HBYTES + 8192);

    k_pipe<<<dim3(2 * BB), dim3(256), 0, stream>>>(
        x, lens, ff_w, ff_b, W_ih0, W_hh0, b0, W_ih1, W_hh1, b1, h0g, flags, pooled);
    k_head<<<dim3(1), dim3(448), 0, stream>>>(pooled, lin_w, lin_b, out);
}